// Round 9
// baseline (1100.159 us; speedup 1.0000x reference)
//
#include <hip/hip_runtime.h>
#include <math.h>
#include <stdint.h>

#define NPOS  32768
#define LOG2N 15
#define BATCH 8
#define TOTAL (BATCH * NPOS)   // 262144 positions
#define HE    ((size_t)16 * TOTAL)   // one h buffer, elements (16 MiB)

typedef __attribute__((ext_vector_type(8))) short short8v;  // 8 bf16 = 4 VGPR
typedef __attribute__((ext_vector_type(4))) float f32x4;    // MFMA C/D

__device__ __forceinline__ float fast_tanh(float x) {
    float t = __expf(-2.f * x);
    return fmaf(2.f, __builtin_amdgcn_rcpf(1.f + t), -1.f);
}
__device__ __forceinline__ float fast_sigmoid(float x) {
    return __builtin_amdgcn_rcpf(1.f + __expf(-x));
}
__device__ __forceinline__ unsigned short bf16rne(float x) {
    unsigned u = __float_as_uint(x);
    u = (u + 0x7fffu + ((u >> 16) & 1u)) >> 16;
    return (unsigned short)u;
}

// ================= init =================
__global__ __launch_bounds__(256) void init_kernel2(
    const int* __restrict__ x_int, const float* __restrict__ W0,
    const float* __restrict__ b0, float* __restrict__ h)
{
    int t0 = (blockIdx.x * 256 + threadIdx.x) * 2;
    int n0 = t0 & (NPOS - 1);
    const float sc = 1.f / 32768.f;
    float xs0  = (n0 >= 1) ? (float)x_int[t0 - 1] * sc : 0.f;
    float xs1  = (float)x_int[t0] * sc;
    float xsp0 = (n0 >= 2) ? (float)x_int[t0 - 2] * sc : 0.f;
    float xsp1 = xs0;
#pragma unroll
    for (int c = 0; c < 16; ++c) {
        float2 o;
        o.x = xs0 + W0[c * 2 + 0] * xsp0 + W0[c * 2 + 1] * xs0 + b0[c];
        o.y = xs1 + W0[c * 2 + 0] * xsp1 + W0[c * 2 + 1] * xs1 + b0[c];
        *(float2*)(h + (size_t)c * TOTAL + t0) = o;
    }
}

// ================= residual layer WITHOUT skip (defer-skip path) =============
__global__ __launch_bounds__(256, 2) void layer_kernel_ns(
    const float* __restrict__ hIn, float* __restrict__ hOut,
    const float* __restrict__ wf, const float* __restrict__ bfv,
    const float* __restrict__ wg, const float* __restrict__ bgv,
    int d)
{
    int t0 = (blockIdx.x * 256 + threadIdx.x) * 2;
    int n0 = t0 & (NPOS - 1);

    float2 hc[16], hp[16];
#pragma unroll
    for (int ic = 0; ic < 16; ++ic)
        hc[ic] = *(const float2*)(hIn + (size_t)ic * TOTAL + t0);

    if (d == 1) {
        bool v = (n0 >= 1);
        int tm = v ? (t0 - 1) : t0;
#pragma unroll
        for (int ic = 0; ic < 16; ++ic) {
            float x = hIn[(size_t)ic * TOTAL + tm];
            hp[ic].x = v ? x : 0.f;
            hp[ic].y = hc[ic].x;
        }
    } else {
        bool v = (n0 >= d);
        int tm = v ? (t0 - d) : t0;
#pragma unroll
        for (int ic = 0; ic < 16; ++ic) {
            float2 x = *(const float2*)(hIn + (size_t)ic * TOTAL + tm);
            hp[ic].x = v ? x.x : 0.f;
            hp[ic].y = v ? x.y : 0.f;
        }
    }

    float2 fa[16], ga[16];
#pragma unroll
    for (int c = 0; c < 16; ++c) {
        fa[c].x = fa[c].y = bfv[c];
        ga[c].x = ga[c].y = bgv[c];
    }
#pragma unroll
    for (int c = 0; c < 16; ++c) {
#pragma unroll
        for (int ic = 0; ic < 16; ++ic) {
            float wf0 = wf[(c * 16 + ic) * 2 + 0];
            float wf1 = wf[(c * 16 + ic) * 2 + 1];
            float wg0 = wg[(c * 16 + ic) * 2 + 0];
            float wg1 = wg[(c * 16 + ic) * 2 + 1];
            fa[c].x = fmaf(wf0, hp[ic].x, fa[c].x);
            fa[c].x = fmaf(wf1, hc[ic].x, fa[c].x);
            fa[c].y = fmaf(wf0, hp[ic].y, fa[c].y);
            fa[c].y = fmaf(wf1, hc[ic].y, fa[c].y);
            ga[c].x = fmaf(wg0, hp[ic].x, ga[c].x);
            ga[c].x = fmaf(wg1, hc[ic].x, ga[c].x);
            ga[c].y = fmaf(wg0, hp[ic].y, ga[c].y);
            ga[c].y = fmaf(wg1, hc[ic].y, ga[c].y);
        }
    }

#pragma unroll
    for (int c = 0; c < 16; ++c) {
        float2 o;
        o.x = fmaf(fast_tanh(fa[c].x), fast_sigmoid(ga[c].x), hc[c].x);
        o.y = fmaf(fast_tanh(fa[c].y), fast_sigmoid(ga[c].y), hc[c].y);
        *(float2*)(hOut + (size_t)c * TOTAL + t0) = o;
    }
}

// ================= final (defer-skip): skip-sum + agg + MFMA logits ==========
// Stage A: thread=(pos=tid&63, scg=tid>>6): skip[8 sc] = Sum_i Wsk_i*H_i + bias
//          -> relu -> LDS sv[64][33] (padded, conflict-free).
// Stage B: wave w computes agg ch [16w,16w+16) from sv -> bf16 swizzled LDS.
// Stage C: MFMA 16x16x32 logits (validated in R8) + softmax + write.
__global__ __launch_bounds__(256, 2) void final_kernel_ds(
    const float* __restrict__ Hbase,
    const float* __restrict__ Wsk,  const float* __restrict__ bskv,
    const float* __restrict__ Wagg, const float* __restrict__ bagg,
    const float* __restrict__ Wout, const float* __restrict__ bout,
    float* __restrict__ out)
{
    __shared__ float sv_lds[64][33];
    __shared__ unsigned short agg_bu[64 * 64];  // [pos][ic] bf16, swizzled
    __shared__ float red_m[64][5];
    __shared__ float red_s[64][5];

    int tid  = threadIdx.x;
    int lane = tid & 63;
    int w    = tid >> 6;
    int posG = blockIdx.x * 64;
    int b    = posG >> LOG2N;
    int nb   = posG & (NPOS - 1);

    // ---- stage A: deferred skip sum
    {
        int lp  = tid & 63;
        int scg = tid >> 6;        // sc chunk [8*scg, 8*scg+8)
        int pos = posG + lp;
        float acc[8];
#pragma unroll
        for (int q = 0; q < 8; ++q) {
            float s = 0.f;
#pragma unroll 1
            for (int i = 0; i < 19; ++i) s += bskv[i * 32 + scg * 8 + q];
            acc[q] = s;
        }
#pragma unroll 1
        for (int i = 0; i < 19; ++i) {
            const float* hb = Hbase + (size_t)i * HE + pos;
            float hv[16];
#pragma unroll
            for (int ic = 0; ic < 16; ++ic) hv[ic] = hb[(size_t)ic * TOTAL];
            const float* wb = Wsk + i * 512 + (scg * 8) * 16;
#pragma unroll
            for (int q = 0; q < 8; ++q)
#pragma unroll
                for (int ic = 0; ic < 16; ++ic)
                    acc[q] = fmaf(wb[q * 16 + ic], hv[ic], acc[q]);
        }
#pragma unroll
        for (int q = 0; q < 8; ++q)
            sv_lds[lp][scg * 8 + q] = fmaxf(acc[q], 0.f);
    }
    __syncthreads();

    // ---- stage B: agg (VALU), thread = (pos=lane, channel group w)
    {
        float sv[32];
#pragma unroll
        for (int sch = 0; sch < 32; ++sch) sv[sch] = sv_lds[lane][sch];

        float r16[16];
#pragma unroll
        for (int a = 0; a < 16; ++a) {
            int ac = w * 16 + a;
            float acc = bagg[ac];
#pragma unroll
            for (int sch = 0; sch < 32; ++sch)
                acc = fmaf(Wagg[ac * 32 + sch], sv[sch], acc);
            r16[a] = fmaxf(acc, 0.f);
        }
#pragma unroll
        for (int q = 0; q < 8; ++q) {
            unsigned pk = (unsigned)bf16rne(r16[2 * q]) |
                          ((unsigned)bf16rne(r16[2 * q + 1]) << 16);
            int icbyte = (w * 16 + 2 * q) * 2;
            int addr   = lane * 128 + (icbyte ^ ((lane & 7) << 4));
            *(unsigned*)(&agg_bu[addr >> 1]) = pk;
        }
    }
    __syncthreads();

    // ---- stage C: MFMA logits
    int lr = lane & 15;
    int lg = lane >> 4;
    int c0 = w * 64;

    short8v afr[4][2];
#pragma unroll
    for (int ct = 0; ct < 4; ++ct) {
#pragma unroll
        for (int kf = 0; kf < 2; ++kf) {
            int cls = c0 + ct * 16 + lr;
            int k0  = kf * 32 + lg * 8;
            const float4* wp = (const float4*)(Wout + (size_t)cls * 64 + k0);
            float4 w0 = wp[0], w1 = wp[1];
            short8v af;
            af[0] = (short)bf16rne(w0.x); af[1] = (short)bf16rne(w0.y);
            af[2] = (short)bf16rne(w0.z); af[3] = (short)bf16rne(w0.w);
            af[4] = (short)bf16rne(w1.x); af[5] = (short)bf16rne(w1.y);
            af[6] = (short)bf16rne(w1.z); af[7] = (short)bf16rne(w1.w);
            afr[ct][kf] = af;
        }
    }

    f32x4 acc[4][4];
#pragma unroll
    for (int pt = 0; pt < 4; ++pt) {
        int pos = pt * 16 + lr;
        int sw  = (pos & 7) << 4;
        const short8v* bp0 = (const short8v*)(&agg_bu[(pos * 128 + ((0 * 64 + lg * 16) ^ sw)) >> 1]);
        const short8v* bp1 = (const short8v*)(&agg_bu[(pos * 128 + ((1 * 64 + lg * 16) ^ sw)) >> 1]);
        short8v bf0 = *bp0;
        short8v bf1 = *bp1;
#pragma unroll
        for (int ct = 0; ct < 4; ++ct) {
            f32x4 c;
#pragma unroll
            for (int r = 0; r < 4; ++r) c[r] = bout[c0 + ct * 16 + lg * 4 + r];
            c = __builtin_amdgcn_mfma_f32_16x16x32_bf16(afr[ct][0], bf0, c, 0, 0, 0);
            c = __builtin_amdgcn_mfma_f32_16x16x32_bf16(afr[ct][1], bf1, c, 0, 0, 0);
            acc[pt][ct] = c;
        }
    }

    // ---- softmax stats
#pragma unroll
    for (int pt = 0; pt < 4; ++pt) {
        float m = -1e30f;
#pragma unroll
        for (int ct = 0; ct < 4; ++ct)
#pragma unroll
            for (int r = 0; r < 4; ++r) m = fmaxf(m, acc[pt][ct][r]);
        m = fmaxf(m, __shfl_xor(m, 16));
        m = fmaxf(m, __shfl_xor(m, 32));
        float s = 0.f;
#pragma unroll
        for (int ct = 0; ct < 4; ++ct)
#pragma unroll
            for (int r = 0; r < 4; ++r) s += __expf(acc[pt][ct][r] - m);
        s += __shfl_xor(s, 16);
        s += __shfl_xor(s, 32);
        int pos = pt * 16 + lr;
        red_m[pos][w] = m;
        red_s[pos][w] = s;
    }
    __syncthreads();

#pragma unroll
    for (int pt = 0; pt < 4; ++pt) {
        int pos = pt * 16 + lr;
        float M = fmaxf(fmaxf(red_m[pos][0], red_m[pos][1]),
                        fmaxf(red_m[pos][2], red_m[pos][3]));
        float S = 0.f;
#pragma unroll
        for (int k = 0; k < 4; ++k) S += red_s[pos][k] * __expf(red_m[pos][k] - M);
        float logZ = M + __logf(S);

        int n = nb + pos;
#pragma unroll
        for (int ct = 0; ct < 4; ++ct) {
#pragma unroll
            for (int r = 0; r < 4; ++r) {
                int cls = c0 + ct * 16 + lg * 4 + r;
                out[((size_t)(b * 256 + cls)) * NPOS + n] = acc[pt][ct][r] - logZ;
            }
        }
    }
}

// =========================================================================
// ================= R8 fallback path (skip-RMW), kept verbatim =============
__global__ __launch_bounds__(256, 2) void layer_kernel2(
    const float* __restrict__ hIn, float* __restrict__ hOut,
    float* __restrict__ skip,
    const float* __restrict__ wf, const float* __restrict__ bfv,
    const float* __restrict__ wg, const float* __restrict__ bgv,
    const float* __restrict__ wsk, const float* __restrict__ bskv,
    int d, int firstLayer)
{
    int t0 = (blockIdx.x * 256 + threadIdx.x) * 2;
    int n0 = t0 & (NPOS - 1);

    float2 hc[16], hp[16];
#pragma unroll
    for (int ic = 0; ic < 16; ++ic)
        hc[ic] = *(const float2*)(hIn + (size_t)ic * TOTAL + t0);

    if (d == 1) {
        bool v = (n0 >= 1);
        int tm = v ? (t0 - 1) : t0;
#pragma unroll
        for (int ic = 0; ic < 16; ++ic) {
            float x = hIn[(size_t)ic * TOTAL + tm];
            hp[ic].x = v ? x : 0.f;
            hp[ic].y = hc[ic].x;
        }
    } else {
        bool v = (n0 >= d);
        int tm = v ? (t0 - d) : t0;
#pragma unroll
        for (int ic = 0; ic < 16; ++ic) {
            float2 x = *(const float2*)(hIn + (size_t)ic * TOTAL + tm);
            hp[ic].x = v ? x.x : 0.f;
            hp[ic].y = v ? x.y : 0.f;
        }
    }

    float2 fa[16], ga[16];
#pragma unroll
    for (int c = 0; c < 16; ++c) {
        fa[c].x = fa[c].y = bfv[c];
        ga[c].x = ga[c].y = bgv[c];
    }
#pragma unroll
    for (int c = 0; c < 16; ++c) {
#pragma unroll
        for (int ic = 0; ic < 16; ++ic) {
            float wf0 = wf[(c * 16 + ic) * 2 + 0];
            float wf1 = wf[(c * 16 + ic) * 2 + 1];
            float wg0 = wg[(c * 16 + ic) * 2 + 0];
            float wg1 = wg[(c * 16 + ic) * 2 + 1];
            fa[c].x = fmaf(wf0, hp[ic].x, fa[c].x);
            fa[c].x = fmaf(wf1, hc[ic].x, fa[c].x);
            fa[c].y = fmaf(wf0, hp[ic].y, fa[c].y);
            fa[c].y = fmaf(wf1, hc[ic].y, fa[c].y);
            ga[c].x = fmaf(wg0, hp[ic].x, ga[c].x);
            ga[c].x = fmaf(wg1, hc[ic].x, ga[c].x);
            ga[c].y = fmaf(wg0, hp[ic].y, ga[c].y);
            ga[c].y = fmaf(wg1, hc[ic].y, ga[c].y);
        }
    }

#pragma unroll
    for (int c = 0; c < 16; ++c) {
        float2 o;
        o.x = fmaf(fast_tanh(fa[c].x), fast_sigmoid(ga[c].x), hc[c].x);
        o.y = fmaf(fast_tanh(fa[c].y), fast_sigmoid(ga[c].y), hc[c].y);
        *(float2*)(hOut + (size_t)c * TOTAL + t0) = o;
    }

#pragma unroll
    for (int sch = 0; sch < 32; ++sch) {
        float2 acc;
        acc.x = acc.y = bskv[sch];
#pragma unroll
        for (int ic = 0; ic < 16; ++ic) {
            float wv = wsk[sch * 16 + ic];
            acc.x = fmaf(wv, hc[ic].x, acc.x);
            acc.y = fmaf(wv, hc[ic].y, acc.y);
        }
        float* sp = skip + (size_t)sch * TOTAL + t0;
        if (firstLayer) {
            *(float2*)sp = acc;
        } else {
            float2 old = *(const float2*)sp;
            acc.x += old.x; acc.y += old.y;
            *(float2*)sp = acc;
        }
    }
}

__global__ __launch_bounds__(256, 2) void final_kernel(
    const float* __restrict__ skip,
    const float* __restrict__ Wagg, const float* __restrict__ bagg,
    const float* __restrict__ Wout, const float* __restrict__ bout,
    float* __restrict__ out)
{
    __shared__ unsigned short agg_bu[64 * 64];
    __shared__ float red_m[64][5];
    __shared__ float red_s[64][5];

    int tid  = threadIdx.x;
    int lane = tid & 63;
    int w    = tid >> 6;
    int posG = blockIdx.x * 64;
    int b    = posG >> LOG2N;
    int nb   = posG & (NPOS - 1);

    {
        int pos = posG + lane;
        float sv[32];
#pragma unroll
        for (int sch = 0; sch < 32; ++sch)
            sv[sch] = fmaxf(skip[(size_t)sch * TOTAL + pos], 0.f);

        float r16[16];
#pragma unroll
        for (int a = 0; a < 16; ++a) {
            int ac = w * 16 + a;
            float acc = bagg[ac];
#pragma unroll
            for (int sch = 0; sch < 32; ++sch)
                acc = fmaf(Wagg[ac * 32 + sch], sv[sch], acc);
            r16[a] = fmaxf(acc, 0.f);
        }
#pragma unroll
        for (int q = 0; q < 8; ++q) {
            unsigned pk = (unsigned)bf16rne(r16[2 * q]) |
                          ((unsigned)bf16rne(r16[2 * q + 1]) << 16);
            int icbyte = (w * 16 + 2 * q) * 2;
            int addr   = lane * 128 + (icbyte ^ ((lane & 7) << 4));
            *(unsigned*)(&agg_bu[addr >> 1]) = pk;
        }
    }
    __syncthreads();

    int lr = lane & 15;
    int lg = lane >> 4;
    int c0 = w * 64;
    short8v afr[4][2];
#pragma unroll
    for (int ct = 0; ct < 4; ++ct) {
#pragma unroll
        for (int kf = 0; kf < 2; ++kf) {
            int cls = c0 + ct * 16 + lr;
            int k0  = kf * 32 + lg * 8;
            const float4* wp = (const float4*)(Wout + (size_t)cls * 64 + k0);
            float4 w0 = wp[0], w1 = wp[1];
            short8v af;
            af[0] = (short)bf16rne(w0.x); af[1] = (short)bf16rne(w0.y);
            af[2] = (short)bf16rne(w0.z); af[3] = (short)bf16rne(w0.w);
            af[4] = (short)bf16rne(w1.x); af[5] = (short)bf16rne(w1.y);
            af[6] = (short)bf16rne(w1.z); af[7] = (short)bf16rne(w1.w);
            afr[ct][kf] = af;
        }
    }

    f32x4 acc[4][4];
#pragma unroll
    for (int pt = 0; pt < 4; ++pt) {
        int pos = pt * 16 + lr;
        int sw  = (pos & 7) << 4;
        const short8v* bp0 = (const short8v*)(&agg_bu[(pos * 128 + ((0 * 64 + lg * 16) ^ sw)) >> 1]);
        const short8v* bp1 = (const short8v*)(&agg_bu[(pos * 128 + ((1 * 64 + lg * 16) ^ sw)) >> 1]);
        short8v bf0 = *bp0;
        short8v bf1 = *bp1;
#pragma unroll
        for (int ct = 0; ct < 4; ++ct) {
            f32x4 c;
#pragma unroll
            for (int r = 0; r < 4; ++r) c[r] = bout[c0 + ct * 16 + lg * 4 + r];
            c = __builtin_amdgcn_mfma_f32_16x16x32_bf16(afr[ct][0], bf0, c, 0, 0, 0);
            c = __builtin_amdgcn_mfma_f32_16x16x32_bf16(afr[ct][1], bf1, c, 0, 0, 0);
            acc[pt][ct] = c;
        }
    }

#pragma unroll
    for (int pt = 0; pt < 4; ++pt) {
        float m = -1e30f;
#pragma unroll
        for (int ct = 0; ct < 4; ++ct)
#pragma unroll
            for (int r = 0; r < 4; ++r) m = fmaxf(m, acc[pt][ct][r]);
        m = fmaxf(m, __shfl_xor(m, 16));
        m = fmaxf(m, __shfl_xor(m, 32));
        float s = 0.f;
#pragma unroll
        for (int ct = 0; ct < 4; ++ct)
#pragma unroll
            for (int r = 0; r < 4; ++r) s += __expf(acc[pt][ct][r] - m);
        s += __shfl_xor(s, 16);
        s += __shfl_xor(s, 32);
        int pos = pt * 16 + lr;
        red_m[pos][w] = m;
        red_s[pos][w] = s;
    }
    __syncthreads();

#pragma unroll
    for (int pt = 0; pt < 4; ++pt) {
        int pos = pt * 16 + lr;
        float M = fmaxf(fmaxf(red_m[pos][0], red_m[pos][1]),
                        fmaxf(red_m[pos][2], red_m[pos][3]));
        float S = 0.f;
#pragma unroll
        for (int k = 0; k < 4; ++k) S += red_s[pos][k] * __expf(red_m[pos][k] - M);
        float logZ = M + __logf(S);

        int n = nb + pos;
#pragma unroll
        for (int ct = 0; ct < 4; ++ct) {
#pragma unroll
            for (int r = 0; r < 4; ++r) {
                int cls = c0 + ct * 16 + lg * 4 + r;
                out[((size_t)(b * 256 + cls)) * NPOS + n] = acc[pt][ct][r] - logZ;
            }
        }
    }
}

extern "C" void kernel_launch(void* const* d_in, const int* in_sizes, int n_in,
                              void* d_out, int out_size, void* d_ws, size_t ws_size,
                              hipStream_t stream)
{
    const int*   x_int = (const int*)  d_in[0];
    const float* W0    = (const float*)d_in[1];
    const float* b0    = (const float*)d_in[2];
    const float* Wf    = (const float*)d_in[3];
    const float* bfv   = (const float*)d_in[4];
    const float* Wg    = (const float*)d_in[5];
    const float* bgv   = (const float*)d_in[6];
    const float* Wsk   = (const float*)d_in[7];
    const float* bskv  = (const float*)d_in[8];
    const float* Wagg  = (const float*)d_in[9];
    const float* bagg  = (const float*)d_in[10];
    const float* Wout  = (const float*)d_in[11];
    const float* bout  = (const float*)d_in[12];
    float* out = (float*)d_out;

    const int grid2 = TOTAL / (256 * 2);   // 512 blocks, 2 pos/thread

    const size_t needDefer = 19 * HE * sizeof(float);   // 304 MiB

    if (ws_size >= needDefer) {
        // ---------- defer-skip path ----------
        float* Hb = (float*)d_ws;   // H_i at Hb + i*HE, i = 0..18

        init_kernel2<<<grid2, 256, 0, stream>>>(x_int, W0, b0, Hb);
        for (int i = 0; i < 18; ++i) {   // layer 18's update is dead code
            int d = 1 << ((i + 1) % 10);
            layer_kernel_ns<<<grid2, 256, 0, stream>>>(
                Hb + (size_t)i * HE, Hb + (size_t)(i + 1) * HE,
                Wf + (size_t)i * 512, bfv + (size_t)i * 16,
                Wg + (size_t)i * 512, bgv + (size_t)i * 16, d);
        }
        final_kernel_ds<<<TOTAL / 64, 256, 0, stream>>>(
            Hb, Wsk, bskv, Wagg, bagg, Wout, bout, out);
    } else {
        // ---------- R8 fallback ----------
        const size_t skE = (size_t)32 * TOTAL;
        float* skipb = (float*)d_ws;
        float *hA, *hB;
        if (ws_size >= (skE + 2 * HE) * sizeof(float)) {
            hA = skipb + skE;
            hB = hA + HE;
        } else {
            hA = out + ((size_t)out_size - 2 * HE);
            hB = hA + HE;
        }

        init_kernel2<<<grid2, 256, 0, stream>>>(x_int, W0, b0, hA);
        float* hin = hA;
        float* hout = hB;
        for (int i = 0; i < 19; ++i) {
            int d = 1 << ((i + 1) % 10);
            layer_kernel2<<<grid2, 256, 0, stream>>>(
                hin, hout, skipb,
                Wf + (size_t)i * 512, bfv + (size_t)i * 16,
                Wg + (size_t)i * 512, bgv + (size_t)i * 16,
                Wsk + (size_t)i * 512, bskv + (size_t)i * 32,
                d, (i == 0) ? 1 : 0);
            float* tmp = hin; hin = hout; hout = tmp;
        }
        final_kernel<<<TOTAL / 64, 256, 0, stream>>>(
            skipb, Wagg, bagg, Wout, bout, out);
    }
}

// Round 10
// 682.793 us; speedup vs baseline: 1.6113x; 1.6113x over previous
//
#include <hip/hip_runtime.h>
#include <math.h>
#include <stdint.h>

#define NPOS  32768
#define LOG2N 15
#define BATCH 8
#define TOTAL (BATCH * NPOS)   // 262144 positions
#define HE    ((size_t)16 * TOTAL)   // one h buffer, elements (16 MiB)

typedef __attribute__((ext_vector_type(8))) short short8v;  // 8 bf16 = 4 VGPR
typedef __attribute__((ext_vector_type(4))) float f32x4;    // MFMA C/D

__device__ __forceinline__ float fast_tanh(float x) {
    float t = __expf(-2.f * x);
    return fmaf(2.f, __builtin_amdgcn_rcpf(1.f + t), -1.f);
}
__device__ __forceinline__ float fast_sigmoid(float x) {
    return __builtin_amdgcn_rcpf(1.f + __expf(-x));
}
__device__ __forceinline__ unsigned short bf16rne(float x) {
    unsigned u = __float_as_uint(x);
    u = (u + 0x7fffu + ((u >> 16) & 1u)) >> 16;
    return (unsigned short)u;
}

// ================= init =================
__global__ __launch_bounds__(256) void init_kernel2(
    const int* __restrict__ x_int, const float* __restrict__ W0,
    const float* __restrict__ b0, float* __restrict__ h)
{
    int t0 = (blockIdx.x * 256 + threadIdx.x) * 2;
    int n0 = t0 & (NPOS - 1);
    const float sc = 1.f / 32768.f;
    float xs0  = (n0 >= 1) ? (float)x_int[t0 - 1] * sc : 0.f;
    float xs1  = (float)x_int[t0] * sc;
    float xsp0 = (n0 >= 2) ? (float)x_int[t0 - 2] * sc : 0.f;
    float xsp1 = xs0;
#pragma unroll
    for (int c = 0; c < 16; ++c) {
        float2 o;
        o.x = xs0 + W0[c * 2 + 0] * xsp0 + W0[c * 2 + 1] * xs0 + b0[c];
        o.y = xs1 + W0[c * 2 + 0] * xsp1 + W0[c * 2 + 1] * xs1 + b0[c];
        *(float2*)(h + (size_t)c * TOTAL + t0) = o;
    }
}

// ================= residual layer WITHOUT skip (defer-skip path) =============
__global__ __launch_bounds__(256, 2) void layer_kernel_ns(
    const float* __restrict__ hIn, float* __restrict__ hOut,
    const float* __restrict__ wf, const float* __restrict__ bfv,
    const float* __restrict__ wg, const float* __restrict__ bgv,
    int d)
{
    int t0 = (blockIdx.x * 256 + threadIdx.x) * 2;
    int n0 = t0 & (NPOS - 1);

    float2 hc[16], hp[16];
#pragma unroll
    for (int ic = 0; ic < 16; ++ic)
        hc[ic] = *(const float2*)(hIn + (size_t)ic * TOTAL + t0);

    if (d == 1) {
        bool v = (n0 >= 1);
        int tm = v ? (t0 - 1) : t0;
#pragma unroll
        for (int ic = 0; ic < 16; ++ic) {
            float x = hIn[(size_t)ic * TOTAL + tm];
            hp[ic].x = v ? x : 0.f;
            hp[ic].y = hc[ic].x;
        }
    } else {
        bool v = (n0 >= d);
        int tm = v ? (t0 - d) : t0;
#pragma unroll
        for (int ic = 0; ic < 16; ++ic) {
            float2 x = *(const float2*)(hIn + (size_t)ic * TOTAL + tm);
            hp[ic].x = v ? x.x : 0.f;
            hp[ic].y = v ? x.y : 0.f;
        }
    }

    float2 fa[16], ga[16];
#pragma unroll
    for (int c = 0; c < 16; ++c) {
        fa[c].x = fa[c].y = bfv[c];
        ga[c].x = ga[c].y = bgv[c];
    }
#pragma unroll
    for (int c = 0; c < 16; ++c) {
#pragma unroll
        for (int ic = 0; ic < 16; ++ic) {
            float wf0 = wf[(c * 16 + ic) * 2 + 0];
            float wf1 = wf[(c * 16 + ic) * 2 + 1];
            float wg0 = wg[(c * 16 + ic) * 2 + 0];
            float wg1 = wg[(c * 16 + ic) * 2 + 1];
            fa[c].x = fmaf(wf0, hp[ic].x, fa[c].x);
            fa[c].x = fmaf(wf1, hc[ic].x, fa[c].x);
            fa[c].y = fmaf(wf0, hp[ic].y, fa[c].y);
            fa[c].y = fmaf(wf1, hc[ic].y, fa[c].y);
            ga[c].x = fmaf(wg0, hp[ic].x, ga[c].x);
            ga[c].x = fmaf(wg1, hc[ic].x, ga[c].x);
            ga[c].y = fmaf(wg0, hp[ic].y, ga[c].y);
            ga[c].y = fmaf(wg1, hc[ic].y, ga[c].y);
        }
    }

#pragma unroll
    for (int c = 0; c < 16; ++c) {
        float2 o;
        o.x = fmaf(fast_tanh(fa[c].x), fast_sigmoid(ga[c].x), hc[c].x);
        o.y = fmaf(fast_tanh(fa[c].y), fast_sigmoid(ga[c].y), hc[c].y);
        *(float2*)(hOut + (size_t)c * TOTAL + t0) = o;
    }
}

// ================= final (defer-skip v2): MFMA skip-sum + agg + MFMA logits ==
// Stage A' (MFMA): skip = Wsk_flat[32][K=304] x H[K][pos], K = i*16+ic, padded
//   to 320. Per wave: pos-tile = [posG+16w, +16), 2 sc-tiles x 10 k-tiles.
//   Each H element read once chip-wide. -> relu -> sv_lds.
// Stage B (VALU, validated): agg ch [16w,16w+16) -> bf16 swizzled LDS.
// Stage C (MFMA, validated): logits + online softmax + write.
__global__ __launch_bounds__(256, 2) void final_kernel_ds2(
    const float* __restrict__ Hbase,
    const float* __restrict__ Wsk,  const float* __restrict__ bskv,
    const float* __restrict__ Wagg, const float* __restrict__ bagg,
    const float* __restrict__ Wout, const float* __restrict__ bout,
    float* __restrict__ out)
{
    __shared__ float sv_lds[64][33];
    __shared__ unsigned short agg_bu[64 * 64];  // [pos][ic] bf16, swizzled
    __shared__ float red_m[64][5];
    __shared__ float red_s[64][5];
    __shared__ float bsum[32];

    int tid  = threadIdx.x;
    int lane = tid & 63;
    int w    = tid >> 6;
    int posG = blockIdx.x * 64;
    int b    = posG >> LOG2N;
    int nb   = posG & (NPOS - 1);

    int lr = lane & 15;
    int lg = lane >> 4;

    // ---- bias sums (skip): bsum[sc] = Sum_i bskv[i][sc]
    if (tid < 32) {
        float s = 0.f;
#pragma unroll 1
        for (int i = 0; i < 19; ++i) s += bskv[i * 32 + tid];
        bsum[tid] = s;
    }

    // ---- stage A': MFMA skip-sum for this wave's 16-position tile
    int posGlob = posG + w * 16 + lr;   // B col / D col for this lane

    f32x4 dsk0 = {0.f, 0.f, 0.f, 0.f};
    f32x4 dsk1 = {0.f, 0.f, 0.f, 0.f};

#pragma unroll
    for (int kt = 0; kt < 10; ++kt) {
        int i   = kt * 2 + (lg >> 1);
        int ic0 = (lg & 1) * 8;
        // B-frag: H[i][ic0+j][posGlob]
        short8v bfr = {0, 0, 0, 0, 0, 0, 0, 0};
        if (i < 19) {
            const float* hb = Hbase + (size_t)i * HE + (size_t)ic0 * TOTAL + posGlob;
#pragma unroll
            for (int j = 0; j < 8; ++j)
                bfr[j] = (short)bf16rne(hb[(size_t)j * TOTAL]);
        }
        // A-frags: Wsk[i][sct*16+lr][ic0..ic0+7]
        short8v af0 = {0, 0, 0, 0, 0, 0, 0, 0};
        short8v af1 = {0, 0, 0, 0, 0, 0, 0, 0};
        if (i < 19) {
            const float4* wp0 = (const float4*)(Wsk + (size_t)i * 512 + (0 * 16 + lr) * 16 + ic0);
            const float4* wp1 = (const float4*)(Wsk + (size_t)i * 512 + (1 * 16 + lr) * 16 + ic0);
            float4 a0 = wp0[0], a1 = wp0[1];
            float4 c0v = wp1[0], c1v = wp1[1];
            af0[0] = (short)bf16rne(a0.x); af0[1] = (short)bf16rne(a0.y);
            af0[2] = (short)bf16rne(a0.z); af0[3] = (short)bf16rne(a0.w);
            af0[4] = (short)bf16rne(a1.x); af0[5] = (short)bf16rne(a1.y);
            af0[6] = (short)bf16rne(a1.z); af0[7] = (short)bf16rne(a1.w);
            af1[0] = (short)bf16rne(c0v.x); af1[1] = (short)bf16rne(c0v.y);
            af1[2] = (short)bf16rne(c0v.z); af1[3] = (short)bf16rne(c0v.w);
            af1[4] = (short)bf16rne(c1v.x); af1[5] = (short)bf16rne(c1v.y);
            af1[6] = (short)bf16rne(c1v.z); af1[7] = (short)bf16rne(c1v.w);
        }
        dsk0 = __builtin_amdgcn_mfma_f32_16x16x32_bf16(af0, bfr, dsk0, 0, 0, 0);
        dsk1 = __builtin_amdgcn_mfma_f32_16x16x32_bf16(af1, bfr, dsk1, 0, 0, 0);
    }

    __syncthreads();   // bsum visible

    // D: col=lr (= local pos w*16+lr), row = lg*4+r (sc within tile)
    {
        int posL = w * 16 + lr;
#pragma unroll
        for (int r = 0; r < 4; ++r) {
            int sc0 = 0 * 16 + lg * 4 + r;
            int sc1 = 1 * 16 + lg * 4 + r;
            sv_lds[posL][sc0] = fmaxf(dsk0[r] + bsum[sc0], 0.f);
            sv_lds[posL][sc1] = fmaxf(dsk1[r] + bsum[sc1], 0.f);
        }
    }
    __syncthreads();

    // ---- stage B: agg (VALU), thread = (pos=lane, channel group w)
    {
        float sv[32];
#pragma unroll
        for (int sch = 0; sch < 32; ++sch) sv[sch] = sv_lds[lane][sch];

        float r16[16];
#pragma unroll
        for (int a = 0; a < 16; ++a) {
            int ac = w * 16 + a;
            float acc = bagg[ac];
#pragma unroll
            for (int sch = 0; sch < 32; ++sch)
                acc = fmaf(Wagg[ac * 32 + sch], sv[sch], acc);
            r16[a] = fmaxf(acc, 0.f);
        }
#pragma unroll
        for (int q = 0; q < 8; ++q) {
            unsigned pk = (unsigned)bf16rne(r16[2 * q]) |
                          ((unsigned)bf16rne(r16[2 * q + 1]) << 16);
            int icbyte = (w * 16 + 2 * q) * 2;
            int addr   = lane * 128 + (icbyte ^ ((lane & 7) << 4));
            *(unsigned*)(&agg_bu[addr >> 1]) = pk;
        }
    }
    __syncthreads();

    // ---- stage C: MFMA logits (validated R8)
    int c0 = w * 64;
    short8v afr[4][2];
#pragma unroll
    for (int ct = 0; ct < 4; ++ct) {
#pragma unroll
        for (int kf = 0; kf < 2; ++kf) {
            int cls = c0 + ct * 16 + lr;
            int k0  = kf * 32 + lg * 8;
            const float4* wp = (const float4*)(Wout + (size_t)cls * 64 + k0);
            float4 w0 = wp[0], w1 = wp[1];
            short8v af;
            af[0] = (short)bf16rne(w0.x); af[1] = (short)bf16rne(w0.y);
            af[2] = (short)bf16rne(w0.z); af[3] = (short)bf16rne(w0.w);
            af[4] = (short)bf16rne(w1.x); af[5] = (short)bf16rne(w1.y);
            af[6] = (short)bf16rne(w1.z); af[7] = (short)bf16rne(w1.w);
            afr[ct][kf] = af;
        }
    }

    f32x4 acc[4][4];
#pragma unroll
    for (int pt = 0; pt < 4; ++pt) {
        int pos = pt * 16 + lr;
        int sw  = (pos & 7) << 4;
        const short8v* bp0 = (const short8v*)(&agg_bu[(pos * 128 + ((0 * 64 + lg * 16) ^ sw)) >> 1]);
        const short8v* bp1 = (const short8v*)(&agg_bu[(pos * 128 + ((1 * 64 + lg * 16) ^ sw)) >> 1]);
        short8v bf0 = *bp0;
        short8v bf1 = *bp1;
#pragma unroll
        for (int ct = 0; ct < 4; ++ct) {
            f32x4 c;
#pragma unroll
            for (int r = 0; r < 4; ++r) c[r] = bout[c0 + ct * 16 + lg * 4 + r];
            c = __builtin_amdgcn_mfma_f32_16x16x32_bf16(afr[ct][0], bf0, c, 0, 0, 0);
            c = __builtin_amdgcn_mfma_f32_16x16x32_bf16(afr[ct][1], bf1, c, 0, 0, 0);
            acc[pt][ct] = c;
        }
    }

#pragma unroll
    for (int pt = 0; pt < 4; ++pt) {
        float m = -1e30f;
#pragma unroll
        for (int ct = 0; ct < 4; ++ct)
#pragma unroll
            for (int r = 0; r < 4; ++r) m = fmaxf(m, acc[pt][ct][r]);
        m = fmaxf(m, __shfl_xor(m, 16));
        m = fmaxf(m, __shfl_xor(m, 32));
        float s = 0.f;
#pragma unroll
        for (int ct = 0; ct < 4; ++ct)
#pragma unroll
            for (int r = 0; r < 4; ++r) s += __expf(acc[pt][ct][r] - m);
        s += __shfl_xor(s, 16);
        s += __shfl_xor(s, 32);
        int pos = pt * 16 + lr;
        red_m[pos][w] = m;
        red_s[pos][w] = s;
    }
    __syncthreads();

#pragma unroll
    for (int pt = 0; pt < 4; ++pt) {
        int pos = pt * 16 + lr;
        float M = fmaxf(fmaxf(red_m[pos][0], red_m[pos][1]),
                        fmaxf(red_m[pos][2], red_m[pos][3]));
        float S = 0.f;
#pragma unroll
        for (int k = 0; k < 4; ++k) S += red_s[pos][k] * __expf(red_m[pos][k] - M);
        float logZ = M + __logf(S);

        int n = nb + pos;
#pragma unroll
        for (int ct = 0; ct < 4; ++ct) {
#pragma unroll
            for (int r = 0; r < 4; ++r) {
                int cls = c0 + ct * 16 + lg * 4 + r;
                out[((size_t)(b * 256 + cls)) * NPOS + n] = acc[pt][ct][r] - logZ;
            }
        }
    }
}

// =========================================================================
// ================= R8 fallback path (skip-RMW), kept verbatim =============
__global__ __launch_bounds__(256, 2) void layer_kernel2(
    const float* __restrict__ hIn, float* __restrict__ hOut,
    float* __restrict__ skip,
    const float* __restrict__ wf, const float* __restrict__ bfv,
    const float* __restrict__ wg, const float* __restrict__ bgv,
    const float* __restrict__ wsk, const float* __restrict__ bskv,
    int d, int firstLayer)
{
    int t0 = (blockIdx.x * 256 + threadIdx.x) * 2;
    int n0 = t0 & (NPOS - 1);

    float2 hc[16], hp[16];
#pragma unroll
    for (int ic = 0; ic < 16; ++ic)
        hc[ic] = *(const float2*)(hIn + (size_t)ic * TOTAL + t0);

    if (d == 1) {
        bool v = (n0 >= 1);
        int tm = v ? (t0 - 1) : t0;
#pragma unroll
        for (int ic = 0; ic < 16; ++ic) {
            float x = hIn[(size_t)ic * TOTAL + tm];
            hp[ic].x = v ? x : 0.f;
            hp[ic].y = hc[ic].x;
        }
    } else {
        bool v = (n0 >= d);
        int tm = v ? (t0 - d) : t0;
#pragma unroll
        for (int ic = 0; ic < 16; ++ic) {
            float2 x = *(const float2*)(hIn + (size_t)ic * TOTAL + tm);
            hp[ic].x = v ? x.x : 0.f;
            hp[ic].y = v ? x.y : 0.f;
        }
    }

    float2 fa[16], ga[16];
#pragma unroll
    for (int c = 0; c < 16; ++c) {
        fa[c].x = fa[c].y = bfv[c];
        ga[c].x = ga[c].y = bgv[c];
    }
#pragma unroll
    for (int c = 0; c < 16; ++c) {
#pragma unroll
        for (int ic = 0; ic < 16; ++ic) {
            float wf0 = wf[(c * 16 + ic) * 2 + 0];
            float wf1 = wf[(c * 16 + ic) * 2 + 1];
            float wg0 = wg[(c * 16 + ic) * 2 + 0];
            float wg1 = wg[(c * 16 + ic) * 2 + 1];
            fa[c].x = fmaf(wf0, hp[ic].x, fa[c].x);
            fa[c].x = fmaf(wf1, hc[ic].x, fa[c].x);
            fa[c].y = fmaf(wf0, hp[ic].y, fa[c].y);
            fa[c].y = fmaf(wf1, hc[ic].y, fa[c].y);
            ga[c].x = fmaf(wg0, hp[ic].x, ga[c].x);
            ga[c].x = fmaf(wg1, hc[ic].x, ga[c].x);
            ga[c].y = fmaf(wg0, hp[ic].y, ga[c].y);
            ga[c].y = fmaf(wg1, hc[ic].y, ga[c].y);
        }
    }

#pragma unroll
    for (int c = 0; c < 16; ++c) {
        float2 o;
        o.x = fmaf(fast_tanh(fa[c].x), fast_sigmoid(ga[c].x), hc[c].x);
        o.y = fmaf(fast_tanh(fa[c].y), fast_sigmoid(ga[c].y), hc[c].y);
        *(float2*)(hOut + (size_t)c * TOTAL + t0) = o;
    }

#pragma unroll
    for (int sch = 0; sch < 32; ++sch) {
        float2 acc;
        acc.x = acc.y = bskv[sch];
#pragma unroll
        for (int ic = 0; ic < 16; ++ic) {
            float wv = wsk[sch * 16 + ic];
            acc.x = fmaf(wv, hc[ic].x, acc.x);
            acc.y = fmaf(wv, hc[ic].y, acc.y);
        }
        float* sp = skip + (size_t)sch * TOTAL + t0;
        if (firstLayer) {
            *(float2*)sp = acc;
        } else {
            float2 old = *(const float2*)sp;
            acc.x += old.x; acc.y += old.y;
            *(float2*)sp = acc;
        }
    }
}

__global__ __launch_bounds__(256, 2) void final_kernel(
    const float* __restrict__ skip,
    const float* __restrict__ Wagg, const float* __restrict__ bagg,
    const float* __restrict__ Wout, const float* __restrict__ bout,
    float* __restrict__ out)
{
    __shared__ unsigned short agg_bu[64 * 64];
    __shared__ float red_m[64][5];
    __shared__ float red_s[64][5];

    int tid  = threadIdx.x;
    int lane = tid & 63;
    int w    = tid >> 6;
    int posG = blockIdx.x * 64;
    int b    = posG >> LOG2N;
    int nb   = posG & (NPOS - 1);

    {
        int pos = posG + lane;
        float sv[32];
#pragma unroll
        for (int sch = 0; sch < 32; ++sch)
            sv[sch] = fmaxf(skip[(size_t)sch * TOTAL + pos], 0.f);

        float r16[16];
#pragma unroll
        for (int a = 0; a < 16; ++a) {
            int ac = w * 16 + a;
            float acc = bagg[ac];
#pragma unroll
            for (int sch = 0; sch < 32; ++sch)
                acc = fmaf(Wagg[ac * 32 + sch], sv[sch], acc);
            r16[a] = fmaxf(acc, 0.f);
        }
#pragma unroll
        for (int q = 0; q < 8; ++q) {
            unsigned pk = (unsigned)bf16rne(r16[2 * q]) |
                          ((unsigned)bf16rne(r16[2 * q + 1]) << 16);
            int icbyte = (w * 16 + 2 * q) * 2;
            int addr   = lane * 128 + (icbyte ^ ((lane & 7) << 4));
            *(unsigned*)(&agg_bu[addr >> 1]) = pk;
        }
    }
    __syncthreads();

    int lr = lane & 15;
    int lg = lane >> 4;
    int c0 = w * 64;
    short8v afr[4][2];
#pragma unroll
    for (int ct = 0; ct < 4; ++ct) {
#pragma unroll
        for (int kf = 0; kf < 2; ++kf) {
            int cls = c0 + ct * 16 + lr;
            int k0  = kf * 32 + lg * 8;
            const float4* wp = (const float4*)(Wout + (size_t)cls * 64 + k0);
            float4 w0 = wp[0], w1 = wp[1];
            short8v af;
            af[0] = (short)bf16rne(w0.x); af[1] = (short)bf16rne(w0.y);
            af[2] = (short)bf16rne(w0.z); af[3] = (short)bf16rne(w0.w);
            af[4] = (short)bf16rne(w1.x); af[5] = (short)bf16rne(w1.y);
            af[6] = (short)bf16rne(w1.z); af[7] = (short)bf16rne(w1.w);
            afr[ct][kf] = af;
        }
    }

    f32x4 acc[4][4];
#pragma unroll
    for (int pt = 0; pt < 4; ++pt) {
        int pos = pt * 16 + lr;
        int sw  = (pos & 7) << 4;
        const short8v* bp0 = (const short8v*)(&agg_bu[(pos * 128 + ((0 * 64 + lg * 16) ^ sw)) >> 1]);
        const short8v* bp1 = (const short8v*)(&agg_bu[(pos * 128 + ((1 * 64 + lg * 16) ^ sw)) >> 1]);
        short8v bf0 = *bp0;
        short8v bf1 = *bp1;
#pragma unroll
        for (int ct = 0; ct < 4; ++ct) {
            f32x4 c;
#pragma unroll
            for (int r = 0; r < 4; ++r) c[r] = bout[c0 + ct * 16 + lg * 4 + r];
            c = __builtin_amdgcn_mfma_f32_16x16x32_bf16(afr[ct][0], bf0, c, 0, 0, 0);
            c = __builtin_amdgcn_mfma_f32_16x16x32_bf16(afr[ct][1], bf1, c, 0, 0, 0);
            acc[pt][ct] = c;
        }
    }

#pragma unroll
    for (int pt = 0; pt < 4; ++pt) {
        float m = -1e30f;
#pragma unroll
        for (int ct = 0; ct < 4; ++ct)
#pragma unroll
            for (int r = 0; r < 4; ++r) m = fmaxf(m, acc[pt][ct][r]);
        m = fmaxf(m, __shfl_xor(m, 16));
        m = fmaxf(m, __shfl_xor(m, 32));
        float s = 0.f;
#pragma unroll
        for (int ct = 0; ct < 4; ++ct)
#pragma unroll
            for (int r = 0; r < 4; ++r) s += __expf(acc[pt][ct][r] - m);
        s += __shfl_xor(s, 16);
        s += __shfl_xor(s, 32);
        int pos = pt * 16 + lr;
        red_m[pos][w] = m;
        red_s[pos][w] = s;
    }
    __syncthreads();

#pragma unroll
    for (int pt = 0; pt < 4; ++pt) {
        int pos = pt * 16 + lr;
        float M = fmaxf(fmaxf(red_m[pos][0], red_m[pos][1]),
                        fmaxf(red_m[pos][2], red_m[pos][3]));
        float S = 0.f;
#pragma unroll
        for (int k = 0; k < 4; ++k) S += red_s[pos][k] * __expf(red_m[pos][k] - M);
        float logZ = M + __logf(S);

        int n = nb + pos;
#pragma unroll
        for (int ct = 0; ct < 4; ++ct) {
#pragma unroll
            for (int r = 0; r < 4; ++r) {
                int cls = c0 + ct * 16 + lg * 4 + r;
                out[((size_t)(b * 256 + cls)) * NPOS + n] = acc[pt][ct][r] - logZ;
            }
        }
    }
}

extern "C" void kernel_launch(void* const* d_in, const int* in_sizes, int n_in,
                              void* d_out, int out_size, void* d_ws, size_t ws_size,
                              hipStream_t stream)
{
    const int*   x_int = (const int*)  d_in[0];
    const float* W0    = (const float*)d_in[1];
    const float* b0    = (const float*)d_in[2];
    const float* Wf    = (const float*)d_in[3];
    const float* bfv   = (const float*)d_in[4];
    const float* Wg    = (const float*)d_in[5];
    const float* bgv   = (const float*)d_in[6];
    const float* Wsk   = (const float*)d_in[7];
    const float* bskv  = (const float*)d_in[8];
    const float* Wagg  = (const float*)d_in[9];
    const float* bagg  = (const float*)d_in[10];
    const float* Wout  = (const float*)d_in[11];
    const float* bout  = (const float*)d_in[12];
    float* out = (float*)d_out;

    const int grid2 = TOTAL / (256 * 2);   // 512 blocks, 2 pos/thread

    const size_t needDefer = 19 * HE * sizeof(float);   // 304 MiB

    if (ws_size >= needDefer) {
        // ---------- defer-skip path ----------
        float* Hb = (float*)d_ws;   // H_i at Hb + i*HE, i = 0..18

        init_kernel2<<<grid2, 256, 0, stream>>>(x_int, W0, b0, Hb);
        for (int i = 0; i < 18; ++i) {   // layer 18's h-update is dead code
            int d = 1 << ((i + 1) % 10);
            layer_kernel_ns<<<grid2, 256, 0, stream>>>(
                Hb + (size_t)i * HE, Hb + (size_t)(i + 1) * HE,
                Wf + (size_t)i * 512, bfv + (size_t)i * 16,
                Wg + (size_t)i * 512, bgv + (size_t)i * 16, d);
        }
        final_kernel_ds2<<<TOTAL / 64, 256, 0, stream>>>(
            Hb, Wsk, bskv, Wagg, bagg, Wout, bout, out);
    } else {
        // ---------- R8 fallback ----------
        const size_t skE = (size_t)32 * TOTAL;
        float* skipb = (float*)d_ws;
        float *hA, *hB;
        if (ws_size >= (skE + 2 * HE) * sizeof(float)) {
            hA = skipb + skE;
            hB = hA + HE;
        } else {
            hA = out + ((size_t)out_size - 2 * HE);
            hB = hA + HE;
        }

        init_kernel2<<<grid2, 256, 0, stream>>>(x_int, W0, b0, hA);
        float* hin = hA;
        float* hout = hB;
        for (int i = 0; i < 19; ++i) {
            int d = 1 << ((i + 1) % 10);
            layer_kernel2<<<grid2, 256, 0, stream>>>(
                hin, hout, skipb,
                Wf + (size_t)i * 512, bfv + (size_t)i * 16,
                Wg + (size_t)i * 512, bgv + (size_t)i * 16,
                Wsk + (size_t)i * 512, bskv + (size_t)i * 32,
                d, (i == 0) ? 1 : 0);
            float* tmp = hin; hin = hout; hout = tmp;
        }
        final_kernel<<<TOTAL / 64, 256, 0, stream>>>(
            skipb, Wagg, bagg, Wout, bout, out);
    }
}